// Round 12
// baseline (126.057 us; speedup 1.0000x reference)
//
#include <hip/hip_runtime.h>
#include <math.h>

// out[b,g, off+v*d+i] = 1/sqrt(128d) * sum_{f,u} x[b,f,off+u*d+i] * psi[f,g,off+u*d+v]
// psi[f,g,c'] = 1/sqrt(512) * sum_n D[n,c'] * w[f,g,n]
//
// Tier A:
//   transpose_D -> prep_all (1024 psi-GEMM blocks + 1024 full-row pack blocks)
//   -> so3_gemm_all: 2980 blocks.  l=6,5: 64x64 tiles (8d^2 blocks each -> 2x the
//      blocks/CU during the dominant segments; occupancy was the measured limiter).
//      l<=4: verified 64x128 tiles (4d^2 blocks).  All: BK=64, TEMPLATED-l body,
//      single-buffered loop (empirical optimum), heavy-first + per-segment bijective
//      XCD chunking, global_load_lds(16B), XOR-swizzled LDS.
//      A = PSI_T rows (g*d+v), B = XP2 rows (b*d+i); lane-fast i -> contiguous d-runs.
// Tier B (ws>=26.4MB): per-l verified fallback.  Tier C (>=17MB): + per-l psi.

typedef float f32x4 __attribute__((ext_vector_type(4)));
typedef short short8 __attribute__((ext_vector_type(8)));
typedef short short4v __attribute__((ext_vector_type(4)));
typedef __bf16 bf8 __attribute__((ext_vector_type(8)));

static __device__ inline bf8 as_bf8(short8 s) {
    union { short8 s; bf8 b; } u; u.s = s; return u.b;
}
static __device__ inline short f2bf(float f) {
    union { float f; unsigned u; } v; v.f = f;
    unsigned r = v.u + 0x7FFFu + ((v.u >> 16) & 1u);   // RNE
    return (short)(r >> 16);
}
static __device__ __forceinline__ void glds16(const short* g, short* l) {
    __builtin_amdgcn_global_load_lds(
        (const __attribute__((address_space(1))) unsigned*)g,
        (__attribute__((address_space(3))) unsigned*)l, 16, 0, 0);
}

static const int OFFS_H[8] = {0, 1, 10, 35, 84, 165, 286, 455};
static const size_t PSIOFF_H[7] = {0, 16384, 163840, 573440, 1376256, 2703360, 4685824};
static constexpr unsigned PSIOFF_C[7] = {0, 16384, 163840, 573440, 1376256, 2703360, 4685824};
static constexpr unsigned XPOFF_C[7] = {0, 32768, 327680, 1146880, 2752512, 5406720, 9371648};
__constant__ int OFFS_D[8] = {0, 1, 10, 35, 84, 165, 286, 455};
__constant__ unsigned PSIOFF_D[7] = {0, 16384, 163840, 573440, 1376256, 2703360, 4685824};

// ---------------- D transpose + bf16: DT[c][n] = D[n][c], c<455, n<512 ----------------
__global__ void transpose_D(const float* __restrict__ D, short* __restrict__ DT) {
    int idx = blockIdx.x * 256 + threadIdx.x;
    if (idx >= 455 * 512) return;
    int n = idx & 511, c = idx >> 9;
    DT[(size_t)c * 512 + n] = f2bf(D[(size_t)n * 455 + c]);
}

// ---------------- psi GEMM body: M=16384, N=512(all-l cols, u-fastest), K=512 --------------
static __device__ __forceinline__ void psi_body(int rawid, const float* __restrict__ w,
                                                const short* __restrict__ DT,
                                                short* __restrict__ PSIall,
                                                short (*As)[72], short (*Bs)[72],
                                                int* colInfo) {
    int id = (rawid & 7) * 128 + (rawid >> 3);         // chunked XCD swizzle (1024%8==0)
    const int nt = id & 3, mt = id >> 2;
    const int tid = threadIdx.x, wave = tid >> 6, lane = tid & 63;
    const int wm = (wave & 1) * 32, wn = (wave >> 1) * 64;

    if (tid < 128) {
        int cp = nt * 128 + tid;
        int info = -1;
        if (cp < 455) {
            int l = 6;
            while (OFFS_D[l] > cp) --l;
            int t = cp - OFFS_D[l];
            int d = 2 * l + 1;
            int v = t / d, u = t - v * d;
            info = (OFFS_D[l] + u * d + v) | (u << 9) | (v << 13) | (l << 17);
        }
        colInfo[tid] = info;
    }
    __syncthreads();

    int brow[4];
#pragma unroll
    for (int c = 0; c < 4; ++c) {
        int inf = colInfo[(tid + c * 256) >> 3];
        brow[c] = (inf < 0) ? 0 : (inf & 511);
    }

    const float* Ag = w + (size_t)(mt * 64) * 512;
    f32x4 acc[2][4] = {};

    for (int k0 = 0; k0 < 512; k0 += 64) {
        __syncthreads();
#pragma unroll
        for (int c = 0; c < 4; ++c) {
            int e = (tid + c * 256) * 4;
            int r = e >> 6, cc = e & 63;
            float4 v = *reinterpret_cast<const float4*>(Ag + (size_t)r * 512 + k0 + cc);
            short4v s;
            s.x = f2bf(v.x); s.y = f2bf(v.y); s.z = f2bf(v.z); s.w = f2bf(v.w);
            *reinterpret_cast<short4v*>(&As[r][cc]) = s;
        }
#pragma unroll
        for (int c = 0; c < 4; ++c) {
            int ch = tid + c * 256;
            int r = ch >> 3, cc = (ch & 7) * 8;
            short8 v = *reinterpret_cast<const short8*>(DT + (size_t)brow[c] * 512 + k0 + cc);
            *reinterpret_cast<short8*>(&Bs[r][cc]) = v;
        }
        __syncthreads();
#pragma unroll
        for (int kf = 0; kf < 2; ++kf) {
            const int kc = kf * 32 + (lane >> 4) * 8;
            short8 af[2], bfr[4];
#pragma unroll
            for (int mi = 0; mi < 2; ++mi)
                af[mi] = *reinterpret_cast<const short8*>(&As[wm + mi * 16 + (lane & 15)][kc]);
#pragma unroll
            for (int ni = 0; ni < 4; ++ni)
                bfr[ni] = *reinterpret_cast<const short8*>(&Bs[wn + ni * 16 + (lane & 15)][kc]);
#pragma unroll
            for (int mi = 0; mi < 2; ++mi)
#pragma unroll
                for (int ni = 0; ni < 4; ++ni)
                    acc[mi][ni] = __builtin_amdgcn_mfma_f32_16x16x32_bf16(
                        as_bf8(af[mi]), as_bf8(bfr[ni]), acc[mi][ni], 0, 0, 0);
        }
    }

    const float s1 = 0.044194173824159216f;  // 1/sqrt(512)
    const int f = mt >> 1;
#pragma unroll
    for (int mi = 0; mi < 2; ++mi)
#pragma unroll
        for (int ni = 0; ni < 4; ++ni) {
            int inf = colInfo[wn + ni * 16 + (lane & 15)];
            if (inf >= 0) {
                int u = (inf >> 9) & 15, v = (inf >> 13) & 15, l = (inf >> 17) & 7;
                int d = 2 * l + 1;
                size_t base = PSIOFF_D[l];
#pragma unroll
                for (int r = 0; r < 4; ++r) {
                    int m = mt * 64 + wm + mi * 16 + (lane >> 4) * 4 + r;
                    int g = m & 127;
                    PSIall[base + (size_t)(g * d + v) * (128 * d) + f * d + u] =
                        f2bf(acc[mi][ni][r] * s1);
                }
            }
        }
}

// ---------------- full-row pack: write one l-slice from a staged full row ----------------
template <int l>
static __device__ __forceinline__ void pack_slice(int b, int fc,
                                                  const short (*Ls)[458],
                                                  short* __restrict__ XPall) {
    constexpr int d = 2 * l + 1;
    constexpr int sz = d * d;
    constexpr int K = 128 * d;
    constexpr int off = l * (2 * l - 1) * (2 * l + 1) / 3;   // sum of (2k+1)^2, k<l
    constexpr int row = 32 * d;
    constexpr int total = 32 * sz;
    short* XP = XPall + XPOFF_C[l];
    for (int e = threadIdx.x; e < total; e += 256) {
        int i = e / row;
        int rem = e - i * row;
        int ff = rem / d, u = rem - ff * d;
        XP[((size_t)b * d + i) * K + (fc * 32 + ff) * d + u] = Ls[ff][off + u * d + i];
    }
}

// ---------------- Tier A prep: psi (1024 blocks) + full-row pack (1024 blocks) -------------
__global__ __launch_bounds__(256) void prep_all(const float* __restrict__ w,
                                                const short* __restrict__ DT,
                                                const float* __restrict__ x,
                                                short* __restrict__ PSIall,
                                                short* __restrict__ XPall) {
    __shared__ __align__(16) char smem[29312];
    const int bid = blockIdx.x;
    if (bid < 1024) {
        short (*As)[72] = (short(*)[72])smem;                // 9216 B
        short (*Bs)[72] = (short(*)[72])(smem + 9216);       // 18432 B
        int* colInfo = (int*)(smem + 27648);                 // 512 B
        psi_body(bid, w, DT, PSIall, As, Bs, colInfo);
    } else {
        const int local = bid - 1024;                        // 0..1023
        const int fc = local & 3, b = local >> 2;
        short (*Ls)[458] = (short(*)[458])smem;              // 32*458*2 = 29312 B
        const float* xb = x + ((size_t)b * 128 + fc * 32) * 455;
        const int tid = threadIdx.x;
        for (int e = tid; e < 32 * 455; e += 256) {
            int ff = e / 455, t = e - ff * 455;              // const divisor -> magic mul
            Ls[ff][t] = f2bf(xb[(size_t)ff * 455 + t]);
        }
        __syncthreads();
        pack_slice<6>(b, fc, Ls, XPall);
        pack_slice<5>(b, fc, Ls, XPall);
        pack_slice<4>(b, fc, Ls, XPall);
        pack_slice<3>(b, fc, Ls, XPall);
        pack_slice<2>(b, fc, Ls, XPall);
        pack_slice<1>(b, fc, Ls, XPall);
        pack_slice<0>(b, fc, Ls, XPall);
    }
}

// standalone psi kernel (tier B)
__global__ __launch_bounds__(256) void psi_gemm_all(const float* __restrict__ w,
                                                    const short* __restrict__ DT,
                                                    short* __restrict__ PSIall) {
    __shared__ short As[64][72];
    __shared__ short Bs[128][72];
    __shared__ int colInfo[128];
    psi_body(blockIdx.y * gridDim.x + blockIdx.x, w, DT, PSIall, As, Bs, colInfo);
}

// ---------------- per-l x packing (tier B/C fallback) ----------------
template <int d>
__global__ __launch_bounds__(256) void pack_x(const float* __restrict__ x,
                                              short* __restrict__ XP, int off) {
    constexpr int sz = d * d;
    constexpr int K = 128 * d;
    const int fc = blockIdx.x, b = blockIdx.y;
    __shared__ short Ls[64][sz + 1];
    const int tid = threadIdx.x;
    const float* xb = x + ((size_t)b * 128 + fc * 64) * 455 + off;
    for (int e = tid; e < 64 * sz; e += 256) {
        int ff = e / sz, t = e - ff * sz;
        Ls[ff][t] = f2bf(xb[(size_t)ff * 455 + t]);
    }
    __syncthreads();
    for (int e = tid; e < 64 * sz; e += 256) {
        int i = e / (64 * d);
        int rem = e - i * (64 * d);
        int ff = rem / d, u = rem - ff * d;
        XP[((size_t)b * d + i) * K + (fc * 64 + ff) * d + u] = Ls[ff][u * d + i];
    }
}

// ---------------- Phase 1 fallback: per-l GEMM M=16384(fg), N=d^2(c), K=512 ----------------
template <int d>
__global__ __launch_bounds__(256) void psi_gemm(const float* __restrict__ w,
                                                const short* __restrict__ DT,
                                                short* __restrict__ PSI, int off) {
    constexpr int sz = d * d;
    constexpr int KP = 128 * d;
    const int mt = blockIdx.x;
    const int nt = blockIdx.y;
    const int tid = threadIdx.x, wave = tid >> 6, lane = tid & 63;
    const int wm = (wave & 1) * 32, wn = (wave >> 1) * 64;

    __shared__ short As[64][72];
    __shared__ short Bs[128][72];

    const float* Ag = w + (size_t)(mt * 64) * 512;
    f32x4 acc[2][4] = {};

    for (int k0 = 0; k0 < 512; k0 += 64) {
        __syncthreads();
#pragma unroll
        for (int c = 0; c < 4; ++c) {
            int e = (tid + c * 256) * 4;
            int r = e >> 6, cc = e & 63;
            float4 v = *reinterpret_cast<const float4*>(Ag + (size_t)r * 512 + k0 + cc);
            short4v s;
            s.x = f2bf(v.x); s.y = f2bf(v.y); s.z = f2bf(v.z); s.w = f2bf(v.w);
            *reinterpret_cast<short4v*>(&As[r][cc]) = s;
        }
#pragma unroll
        for (int c = 0; c < 4; ++c) {
            int ch = tid + c * 256;
            int r = ch >> 3, cc = (ch & 7) * 8;
            int gc = nt * 128 + r;
            int row = off + (gc < sz ? gc : 0);
            short8 v = *reinterpret_cast<const short8*>(DT + (size_t)row * 512 + k0 + cc);
            *reinterpret_cast<short8*>(&Bs[r][cc]) = v;
        }
        __syncthreads();
#pragma unroll
        for (int kf = 0; kf < 2; ++kf) {
            const int kc = kf * 32 + (lane >> 4) * 8;
            short8 af[2], bfr[4];
#pragma unroll
            for (int mi = 0; mi < 2; ++mi)
                af[mi] = *reinterpret_cast<const short8*>(&As[wm + mi * 16 + (lane & 15)][kc]);
#pragma unroll
            for (int ni = 0; ni < 4; ++ni)
                bfr[ni] = *reinterpret_cast<const short8*>(&Bs[wn + ni * 16 + (lane & 15)][kc]);
#pragma unroll
            for (int mi = 0; mi < 2; ++mi)
#pragma unroll
                for (int ni = 0; ni < 4; ++ni)
                    acc[mi][ni] = __builtin_amdgcn_mfma_f32_16x16x32_bf16(
                        as_bf8(af[mi]), as_bf8(bfr[ni]), acc[mi][ni], 0, 0, 0);
        }
    }

    const float s1 = 0.044194173824159216f;  // 1/sqrt(512)
#pragma unroll
    for (int mi = 0; mi < 2; ++mi)
#pragma unroll
        for (int ni = 0; ni < 4; ++ni) {
            int cix = nt * 128 + wn + ni * 16 + (lane & 15);
            if (cix < sz) {
                int u = cix / d, v = cix - u * d;
#pragma unroll
                for (int r = 0; r < 4; ++r) {
                    int m = mt * 64 + wm + mi * 16 + (lane >> 4) * 4 + r;
                    int f = m >> 7, g = m & 127;
                    PSI[(size_t)(g * d + v) * KP + f * d + u] = f2bf(acc[mi][ni][r] * s1);
                }
            }
        }
}

// ---------------- Phase 2 tier A: 64x128 body (l<=4), single-buffered ----------------
template <int l>
static __device__ __forceinline__ void so3_body(int pp,
                                                const short* __restrict__ XPall,
                                                const short* __restrict__ PSIall,
                                                float* __restrict__ out,
                                                short* As, short* Bs) {
    constexpr int d = 2 * l + 1;
    constexpr int K = 128 * d;
    constexpr int S = 4 * d * d;                     // segment size, S % 8 == 4
    constexpr int q = S >> 3;
    constexpr int off = l * (2 * l - 1) * (2 * l + 1) / 3;
    constexpr int mtiles = 2 * d;

    const int xcd = pp & 7, pos = pp >> 3;           // per-segment bijective XCD chunk
    const int local = (xcd < 4 ? xcd * (q + 1) : 4 * (q + 1) + (xcd - 4) * q) + pos;
    const int mt = local % mtiles, nt = local / mtiles;   // consecutive locals share nt

    const int tid = threadIdx.x, wave = tid >> 6, lane = tid & 63;
    const int wm = (wave & 1) * 32, wn = (wave >> 1) * 64;

    const short* Ag = PSIall + PSIOFF_C[l] + (size_t)(mt * 64) * K;
    const short* Bg = XPall + XPOFF_C[l] + (size_t)(nt * 128) * K;

    const int lrow = lane >> 3;                      // 0..7
    const int scol = (((lane & 7) ^ lrow) << 3);     // inverse-swizzled global slot (shorts)

    f32x4 acc[2][4] = {};

#pragma unroll 1
    for (int k0 = 0; k0 < K; k0 += 64) {
        __syncthreads();                             // all waves done reading prev tile
#pragma unroll
        for (int c = 0; c < 2; ++c)                  // A: rows wave*16 + 8c + lrow
            glds16(Ag + (size_t)(wave * 16 + 8 * c + lrow) * K + k0 + scol,
                   &As[(wave * 16 + 8 * c) * 64]);
#pragma unroll
        for (int c = 0; c < 4; ++c)                  // B: rows wave*32 + 8c + lrow
            glds16(Bg + (size_t)(wave * 32 + 8 * c + lrow) * K + k0 + scol,
                   &Bs[(wave * 32 + 8 * c) * 64]);
        __syncthreads();                             // vmcnt drained -> tile ready
#pragma unroll
        for (int kf = 0; kf < 2; ++kf) {
            const int so = (((kf * 4 + (lane >> 4)) ^ (lane & 7)) << 3);
            short8 af[2], bfr[4];
#pragma unroll
            for (int mi = 0; mi < 2; ++mi)
                af[mi] = *reinterpret_cast<const short8*>(
                    &As[(wm + mi * 16 + (lane & 15)) * 64 + so]);
#pragma unroll
            for (int ni = 0; ni < 4; ++ni)
                bfr[ni] = *reinterpret_cast<const short8*>(
                    &Bs[(wn + ni * 16 + (lane & 15)) * 64 + so]);
#pragma unroll
            for (int mi = 0; mi < 2; ++mi)
#pragma unroll
                for (int ni = 0; ni < 4; ++ni)
                    acc[mi][ni] = __builtin_amdgcn_mfma_f32_16x16x32_bf16(
                        as_bf8(af[mi]), as_bf8(bfr[ni]), acc[mi][ni], 0, 0, 0);
        }
    }

    const float s2 = rsqrtf(128.0f * (float)d);      // folds: d is constexpr
#pragma unroll
    for (int mi = 0; mi < 2; ++mi)
#pragma unroll
        for (int ni = 0; ni < 4; ++ni) {
            int n = nt * 128 + wn + ni * 16 + (lane & 15);
            int b = n / d, i = n - b * d;            // constexpr d -> magic mul
#pragma unroll
            for (int r = 0; r < 4; ++r) {
                int m = mt * 64 + wm + mi * 16 + (lane >> 4) * 4 + r;
                int g = m / d, v = m - g * d;
                out[((size_t)b * 128 + g) * 455 + off + v * d + i] = acc[mi][ni][r] * s2;
            }
        }
}

// ---------------- Phase 2 tier A: 64x64 body (l=5,6) -- 2x blocks/CU ----------------
// Segment size 8d^2 (multiple of 8 -> trivial XCD chunk).  4 waves, each a 32x32
// quadrant: wm=(wave&1)*32, wn=(wave>>1)*32, acc[2][2].  Staging mirrors the verified
// 64-row A pattern on both operands; swizzle identities hold (wm,wn,mi*16 mult of 8).
template <int l>
static __device__ __forceinline__ void so3_body64(int pp,
                                                  const short* __restrict__ XPall,
                                                  const short* __restrict__ PSIall,
                                                  float* __restrict__ out,
                                                  short* As, short* Bs) {
    constexpr int d = 2 * l + 1;
    constexpr int K = 128 * d;
    constexpr int S = 8 * d * d;                     // S % 8 == 0
    constexpr int q = S >> 3;
    constexpr int off = l * (2 * l - 1) * (2 * l + 1) / 3;
    constexpr int mtiles = 2 * d;                    // M = 128d -> 2d tiles of 64

    const int xcd = pp & 7, pos = pp >> 3;
    const int local = xcd * q + pos;                 // bijective (S multiple of 8)
    const int mt = local % mtiles, nt = local / mtiles;   // consecutive locals share nt

    const int tid = threadIdx.x, wave = tid >> 6, lane = tid & 63;
    const int wm = (wave & 1) * 32, wn = (wave >> 1) * 32;

    const short* Ag = PSIall + PSIOFF_C[l] + (size_t)(mt * 64) * K;
    const short* Bg = XPall + XPOFF_C[l] + (size_t)(nt * 64) * K;

    const int lrow = lane >> 3;                      // 0..7
    const int scol = (((lane & 7) ^ lrow) << 3);     // inverse-swizzled global slot (shorts)

    f32x4 acc[2][2] = {};

#pragma unroll 1
    for (int k0 = 0; k0 < K; k0 += 64) {
        __syncthreads();
#pragma unroll
        for (int c = 0; c < 2; ++c)                  // A: rows wave*16 + 8c + lrow
            glds16(Ag + (size_t)(wave * 16 + 8 * c + lrow) * K + k0 + scol,
                   &As[(wave * 16 + 8 * c) * 64]);
#pragma unroll
        for (int c = 0; c < 2; ++c)                  // B: rows wave*16 + 8c + lrow
            glds16(Bg + (size_t)(wave * 16 + 8 * c + lrow) * K + k0 + scol,
                   &Bs[(wave * 16 + 8 * c) * 64]);
        __syncthreads();
#pragma unroll
        for (int kf = 0; kf < 2; ++kf) {
            const int so = (((kf * 4 + (lane >> 4)) ^ (lane & 7)) << 3);
            short8 af[2], bfr[2];
#pragma unroll
            for (int mi = 0; mi < 2; ++mi)
                af[mi] = *reinterpret_cast<const short8*>(
                    &As[(wm + mi * 16 + (lane & 15)) * 64 + so]);
#pragma unroll
            for (int ni = 0; ni < 2; ++ni)
                bfr[ni] = *reinterpret_cast<const short8*>(
                    &Bs[(wn + ni * 16 + (lane & 15)) * 64 + so]);
#pragma unroll
            for (int mi = 0; mi < 2; ++mi)
#pragma unroll
                for (int ni = 0; ni < 2; ++ni)
                    acc[mi][ni] = __builtin_amdgcn_mfma_f32_16x16x32_bf16(
                        as_bf8(af[mi]), as_bf8(bfr[ni]), acc[mi][ni], 0, 0, 0);
        }
    }

    const float s2 = rsqrtf(128.0f * (float)d);
#pragma unroll
    for (int mi = 0; mi < 2; ++mi)
#pragma unroll
        for (int ni = 0; ni < 2; ++ni) {
            int n = nt * 64 + wn + ni * 16 + (lane & 15);
            int b = n / d, i = n - b * d;
#pragma unroll
            for (int r = 0; r < 4; ++r) {
                int m = mt * 64 + wm + mi * 16 + (lane >> 4) * 4 + r;
                int g = m / d, v = m - g * d;
                out[((size_t)b * 128 + g) * 455 + off + v * d + i] = acc[mi][ni][r] * s2;
            }
        }
}

// segments, descending l: l6 8d^2=1352, l5 968, then 4d^2: 324,196,100,36,4 -> 2980
__global__ __launch_bounds__(256) void so3_gemm_all(const short* __restrict__ XPall,
                                                    const short* __restrict__ PSIall,
                                                    float* __restrict__ out) {
    __shared__ short As[64 * 64];      // 8 KB
    __shared__ short Bs[128 * 64];     // 16 KB (64x64 bodies use the first half)
    const int p = blockIdx.x;
    if (p < 1352)      so3_body64<6>(p,        XPall, PSIall, out, As, Bs);
    else if (p < 2320) so3_body64<5>(p - 1352, XPall, PSIall, out, As, Bs);
    else if (p < 2644) so3_body<4>(p - 2320, XPall, PSIall, out, As, Bs);
    else if (p < 2840) so3_body<3>(p - 2644, XPall, PSIall, out, As, Bs);
    else if (p < 2940) so3_body<2>(p - 2840, XPall, PSIall, out, As, Bs);
    else if (p < 2976) so3_body<1>(p - 2940, XPall, PSIall, out, As, Bs);
    else               so3_body<0>(p - 2976, XPall, PSIall, out, As, Bs);
}

// ---------------- Phase 2 tier B/C: round-1 verified per-l GEMM (reg-staged) ---------------
template <int d>
__global__ __launch_bounds__(256) void so3_gemm_fb(const short* __restrict__ XP,
                                                   const short* __restrict__ PSI,
                                                   float* __restrict__ out, int off) {
    constexpr int K = 128 * d;
    constexpr int GX = 2 * d;
    constexpr int NWG = 4 * d * d;
    int id = blockIdx.y * gridDim.x + blockIdx.x;
    {
        constexpr int q = NWG >> 3, rr = NWG & 7;
        int xcd = id & 7, pos = id >> 3;
        id = (xcd < rr ? xcd * (q + 1) : rr * (q + 1) + (xcd - rr) * q) + pos;
    }
    const int mt = id % GX, nt = id / GX;
    const int tid = threadIdx.x, wave = tid >> 6, lane = tid & 63;
    const int wm = (wave & 1) * 32, wn = (wave >> 1) * 64;

    __shared__ short As[64][72];
    __shared__ short Bs[128][72];

    const short* Ag = PSI + (size_t)(mt * 64) * K;
    const short* Bg = XP + (size_t)(nt * 128) * K;
    f32x4 acc[2][4] = {};

    for (int k0 = 0; k0 < K; k0 += 64) {
        __syncthreads();
#pragma unroll
        for (int c = 0; c < 2; ++c) {
            int ch = tid + c * 256;
            int r = ch >> 3, cc = (ch & 7) * 8;
            *reinterpret_cast<short8*>(&As[r][cc]) =
                *reinterpret_cast<const short8*>(Ag + (size_t)r * K + k0 + cc);
        }
#pragma unroll
        for (int c = 0; c < 4; ++c) {
            int ch = tid + c * 256;
            int r = ch >> 3, cc = (ch & 7) * 8;
            *reinterpret_cast<short8*>(&Bs[r][cc]) =
                *reinterpret_cast<const short8*>(Bg + (size_t)r * K + k0 + cc);
        }
        __syncthreads();
#pragma unroll
        for (int kf = 0; kf < 2; ++kf) {
            const int kc = kf * 32 + (lane >> 4) * 8;
            short8 af[2], bfr[4];
#pragma unroll
            for (int mi = 0; mi < 2; ++mi)
                af[mi] = *reinterpret_cast<const short8*>(&As[wm + mi * 16 + (lane & 15)][kc]);
#pragma unroll
            for (int ni = 0; ni < 4; ++ni)
                bfr[ni] = *reinterpret_cast<const short8*>(&Bs[wn + ni * 16 + (lane & 15)][kc]);
#pragma unroll
            for (int mi = 0; mi < 2; ++mi)
#pragma unroll
                for (int ni = 0; ni < 4; ++ni)
                    acc[mi][ni] = __builtin_amdgcn_mfma_f32_16x16x32_bf16(
                        as_bf8(af[mi]), as_bf8(bfr[ni]), acc[mi][ni], 0, 0, 0);
        }
    }

    const float s2 = rsqrtf(128.0f * (float)d);
#pragma unroll
    for (int mi = 0; mi < 2; ++mi)
#pragma unroll
        for (int ni = 0; ni < 4; ++ni) {
            int n = nt * 128 + wn + ni * 16 + (lane & 15);
            int b = n / d, i = n - b * d;
#pragma unroll
            for (int r = 0; r < 4; ++r) {
                int m = mt * 64 + wm + mi * 16 + (lane >> 4) * 4 + r;
                int g = m / d, v = m - g * d;
                out[((size_t)b * 128 + g) * 455 + off + v * d + i] = acc[mi][ni][r] * s2;
            }
        }
}

// ---------------- drivers ----------------
template <int l>
static void run_l_fb(const float* x, const float* w, const short* DT, short* PSIbase,
                     short* XP, float* out, bool fused, hipStream_t stream) {
    constexpr int d = 2 * l + 1;
    const int off = OFFS_H[l];
    if (!fused) {
        constexpr int sz = d * d;
        constexpr int ntiles = (sz + 127) / 128;
        psi_gemm<d><<<dim3(256, ntiles), 256, 0, stream>>>(w, DT, PSIbase, off);
    }
    pack_x<d><<<dim3(2, 256), 256, 0, stream>>>(x, XP, off);
    const short* P = fused ? (PSIbase + PSIOFF_H[l]) : PSIbase;
    so3_gemm_fb<d><<<dim3(2 * d, 2 * d), 256, 0, stream>>>(XP, P, out, off);
}

extern "C" void kernel_launch(void* const* d_in, const int* in_sizes, int n_in,
                              void* d_out, int out_size, void* d_ws, size_t ws_size,
                              hipStream_t stream) {
    const float* x = (const float*)d_in[0];   // [256,128,455]
    const float* w = (const float*)d_in[1];   // [128,128,512]
    const float* D = (const float*)d_in[2];   // [512,455]
    float* out = (float*)d_out;

    char* ws = (char*)d_ws;
    const size_t dtBytes      = (size_t)455 * 512 * 2;      //    465,920
    const size_t psiAllBytes  = (size_t)7454720 * 2;        // 14,909,440 (all-l PSI)
    const size_t psiSlotBytes = (size_t)1664 * 1664 * 2;    //  5,537,792 (l=6 slot)
    const size_t xpL6Bytes    = (size_t)3328 * 1664 * 2;    // 11,067,392 (l=6 XP2)
    const size_t xpAllBytes   = (size_t)14909440 * 2;       // 29,818,880 (all-l XP2)

    short* DT = (short*)ws;
    transpose_D<<<(455 * 512 + 255) / 256, 256, 0, stream>>>(D, DT);

    if (ws_size >= dtBytes + psiAllBytes + xpAllBytes) {            // Tier A: 45.2 MB
        short* PSIall = (short*)(ws + dtBytes);
        short* XPall  = (short*)(ws + dtBytes + psiAllBytes);
        prep_all<<<dim3(2048), 256, 0, stream>>>(w, DT, x, PSIall, XPall);
        so3_gemm_all<<<dim3(2980), 256, 0, stream>>>(XPall, PSIall, out);
        return;
    }

    const bool fused = ws_size >= dtBytes + psiAllBytes + xpL6Bytes;  // Tier B: 26.4 MB
    short* PSIbase = (short*)(ws + dtBytes);
    short* XP = (short*)(ws + dtBytes + (fused ? psiAllBytes : psiSlotBytes));
    if (fused)
        psi_gemm_all<<<dim3(4, 256), 256, 0, stream>>>(w, DT, PSIbase);

    run_l_fb<0>(x, w, DT, PSIbase, XP, out, fused, stream);
    run_l_fb<1>(x, w, DT, PSIbase, XP, out, fused, stream);
    run_l_fb<2>(x, w, DT, PSIbase, XP, out, fused, stream);
    run_l_fb<3>(x, w, DT, PSIbase, XP, out, fused, stream);
    run_l_fb<4>(x, w, DT, PSIbase, XP, out, fused, stream);
    run_l_fb<5>(x, w, DT, PSIbase, XP, out, fused, stream);
    run_l_fb<6>(x, w, DT, PSIbase, XP, out, fused, stream);
}

// Round 13
// 116.792 us; speedup vs baseline: 1.0793x; 1.0793x over previous
//
#include <hip/hip_runtime.h>
#include <math.h>

// out[b,g, off+v*d+i] = 1/sqrt(128d) * sum_{f,u} x[b,f,off+u*d+i] * psi[f,g,off+u*d+v]
// psi[f,g,c'] = 1/sqrt(512) * sum_n D[n,c'] * w[f,g,n]
//
// Tier A:
//   transpose_D -> prep_all (1024 psi-GEMM blocks + 1024 full-row pack blocks, float4 reads)
//   -> so3_gemm_all: 1820 blocks (sum 4d^2), 64x128 tile, BK=64, TEMPLATED-l body,
//      SINGLE-BUFFERED loop (empirical optimum of 10 schedule/tile variants; within ~5%
//      of the measured ~12.5 TB/s staging-bandwidth floor for this working set),
//      heavy-first segments + per-segment bijective XCD chunking,
//      global_load_lds(16B), XOR-swizzled LDS (linear dest / inv-swz src / swz read).
//      A = PSI_T rows (g*d+v), B = XP2 rows (b*d+i); lane-fast i -> contiguous d-runs.
// Tier B (ws>=26.4MB): per-l verified fallback.  Tier C (>=17MB): + per-l psi.

typedef float f32x4 __attribute__((ext_vector_type(4)));
typedef short short8 __attribute__((ext_vector_type(8)));
typedef short short4v __attribute__((ext_vector_type(4)));
typedef __bf16 bf8 __attribute__((ext_vector_type(8)));

static __device__ inline bf8 as_bf8(short8 s) {
    union { short8 s; bf8 b; } u; u.s = s; return u.b;
}
static __device__ inline short f2bf(float f) {
    union { float f; unsigned u; } v; v.f = f;
    unsigned r = v.u + 0x7FFFu + ((v.u >> 16) & 1u);   // RNE
    return (short)(r >> 16);
}
static __device__ __forceinline__ void glds16(const short* g, short* l) {
    __builtin_amdgcn_global_load_lds(
        (const __attribute__((address_space(1))) unsigned*)g,
        (__attribute__((address_space(3))) unsigned*)l, 16, 0, 0);
}

static const int OFFS_H[8] = {0, 1, 10, 35, 84, 165, 286, 455};
static const size_t PSIOFF_H[7] = {0, 16384, 163840, 573440, 1376256, 2703360, 4685824};
static constexpr unsigned PSIOFF_C[7] = {0, 16384, 163840, 573440, 1376256, 2703360, 4685824};
static constexpr unsigned XPOFF_C[7] = {0, 32768, 327680, 1146880, 2752512, 5406720, 9371648};
__constant__ int OFFS_D[8] = {0, 1, 10, 35, 84, 165, 286, 455};
__constant__ unsigned PSIOFF_D[7] = {0, 16384, 163840, 573440, 1376256, 2703360, 4685824};

// ---------------- D transpose + bf16: DT[c][n] = D[n][c], c<455, n<512 ----------------
__global__ void transpose_D(const float* __restrict__ D, short* __restrict__ DT) {
    int idx = blockIdx.x * 256 + threadIdx.x;
    if (idx >= 455 * 512) return;
    int n = idx & 511, c = idx >> 9;
    DT[(size_t)c * 512 + n] = f2bf(D[(size_t)n * 455 + c]);
}

// ---------------- psi GEMM body: M=16384, N=512(all-l cols, u-fastest), K=512 --------------
static __device__ __forceinline__ void psi_body(int rawid, const float* __restrict__ w,
                                                const short* __restrict__ DT,
                                                short* __restrict__ PSIall,
                                                short (*As)[72], short (*Bs)[72],
                                                int* colInfo) {
    int id = (rawid & 7) * 128 + (rawid >> 3);         // chunked XCD swizzle (1024%8==0)
    const int nt = id & 3, mt = id >> 2;
    const int tid = threadIdx.x, wave = tid >> 6, lane = tid & 63;
    const int wm = (wave & 1) * 32, wn = (wave >> 1) * 64;

    if (tid < 128) {
        int cp = nt * 128 + tid;
        int info = -1;
        if (cp < 455) {
            int l = 6;
            while (OFFS_D[l] > cp) --l;
            int t = cp - OFFS_D[l];
            int d = 2 * l + 1;
            int v = t / d, u = t - v * d;
            info = (OFFS_D[l] + u * d + v) | (u << 9) | (v << 13) | (l << 17);
        }
        colInfo[tid] = info;
    }
    __syncthreads();

    int brow[4];
#pragma unroll
    for (int c = 0; c < 4; ++c) {
        int inf = colInfo[(tid + c * 256) >> 3];
        brow[c] = (inf < 0) ? 0 : (inf & 511);
    }

    const float* Ag = w + (size_t)(mt * 64) * 512;
    f32x4 acc[2][4] = {};

    for (int k0 = 0; k0 < 512; k0 += 64) {
        __syncthreads();
#pragma unroll
        for (int c = 0; c < 4; ++c) {
            int e = (tid + c * 256) * 4;
            int r = e >> 6, cc = e & 63;
            float4 v = *reinterpret_cast<const float4*>(Ag + (size_t)r * 512 + k0 + cc);
            short4v s;
            s.x = f2bf(v.x); s.y = f2bf(v.y); s.z = f2bf(v.z); s.w = f2bf(v.w);
            *reinterpret_cast<short4v*>(&As[r][cc]) = s;
        }
#pragma unroll
        for (int c = 0; c < 4; ++c) {
            int ch = tid + c * 256;
            int r = ch >> 3, cc = (ch & 7) * 8;
            short8 v = *reinterpret_cast<const short8*>(DT + (size_t)brow[c] * 512 + k0 + cc);
            *reinterpret_cast<short8*>(&Bs[r][cc]) = v;
        }
        __syncthreads();
#pragma unroll
        for (int kf = 0; kf < 2; ++kf) {
            const int kc = kf * 32 + (lane >> 4) * 8;
            short8 af[2], bfr[4];
#pragma unroll
            for (int mi = 0; mi < 2; ++mi)
                af[mi] = *reinterpret_cast<const short8*>(&As[wm + mi * 16 + (lane & 15)][kc]);
#pragma unroll
            for (int ni = 0; ni < 4; ++ni)
                bfr[ni] = *reinterpret_cast<const short8*>(&Bs[wn + ni * 16 + (lane & 15)][kc]);
#pragma unroll
            for (int mi = 0; mi < 2; ++mi)
#pragma unroll
                for (int ni = 0; ni < 4; ++ni)
                    acc[mi][ni] = __builtin_amdgcn_mfma_f32_16x16x32_bf16(
                        as_bf8(af[mi]), as_bf8(bfr[ni]), acc[mi][ni], 0, 0, 0);
        }
    }

    const float s1 = 0.044194173824159216f;  // 1/sqrt(512)
    const int f = mt >> 1;
#pragma unroll
    for (int mi = 0; mi < 2; ++mi)
#pragma unroll
        for (int ni = 0; ni < 4; ++ni) {
            int inf = colInfo[wn + ni * 16 + (lane & 15)];
            if (inf >= 0) {
                int u = (inf >> 9) & 15, v = (inf >> 13) & 15, l = (inf >> 17) & 7;
                int d = 2 * l + 1;
                size_t base = PSIOFF_D[l];
#pragma unroll
                for (int r = 0; r < 4; ++r) {
                    int m = mt * 64 + wm + mi * 16 + (lane >> 4) * 4 + r;
                    int g = m & 127;
                    PSIall[base + (size_t)(g * d + v) * (128 * d) + f * d + u] =
                        f2bf(acc[mi][ni][r] * s1);
                }
            }
        }
}

// ---------------- full-row pack: write one l-slice from a staged full row ----------------
template <int l>
static __device__ __forceinline__ void pack_slice(int b, int fc,
                                                  const short (*Ls)[458],
                                                  short* __restrict__ XPall) {
    constexpr int d = 2 * l + 1;
    constexpr int sz = d * d;
    constexpr int K = 128 * d;
    constexpr int off = l * (2 * l - 1) * (2 * l + 1) / 3;   // sum of (2k+1)^2, k<l
    constexpr int row = 32 * d;
    constexpr int total = 32 * sz;
    short* XP = XPall + XPOFF_C[l];
    for (int e = threadIdx.x; e < total; e += 256) {
        int i = e / row;
        int rem = e - i * row;
        int ff = rem / d, u = rem - ff * d;
        XP[((size_t)b * d + i) * K + (fc * 32 + ff) * d + u] = Ls[ff][off + u * d + i];
    }
}

// ---------------- Tier A prep: psi (1024 blocks) + full-row pack (1024 blocks) -------------
__global__ __launch_bounds__(256) void prep_all(const float* __restrict__ w,
                                                const short* __restrict__ DT,
                                                const float* __restrict__ x,
                                                short* __restrict__ PSIall,
                                                short* __restrict__ XPall) {
    __shared__ __align__(16) char smem[29312];
    const int bid = blockIdx.x;
    if (bid < 1024) {
        short (*As)[72] = (short(*)[72])smem;                // 9216 B
        short (*Bs)[72] = (short(*)[72])(smem + 9216);       // 18432 B
        int* colInfo = (int*)(smem + 27648);                 // 512 B
        psi_body(bid, w, DT, PSIall, As, Bs, colInfo);
    } else {
        const int local = bid - 1024;                        // 0..1023
        const int fc = local & 3, b = local >> 2;
        short (*Ls)[458] = (short(*)[458])smem;              // 32*458*2 = 29312 B
        // chunk = 32 contiguous rows = 14560 floats; (b*128+fc*32)*455 % 4 == 0
        // -> 16B-aligned float4 loads over the whole chunk.
        const float* xb = x + ((size_t)b * 128 + fc * 32) * 455;
        const int tid = threadIdx.x;
        for (int e4 = tid; e4 < 3640; e4 += 256) {           // 14560/4
            float4 v = *reinterpret_cast<const float4*>(xb + (size_t)e4 * 4);
            int e = e4 * 4;
#pragma unroll
            for (int j = 0; j < 4; ++j) {
                int ee = e + j;
                int ff = ee / 455, t = ee - ff * 455;        // const divisor -> magic mul
                Ls[ff][t] = f2bf((&v.x)[j]);
            }
        }
        __syncthreads();
        pack_slice<6>(b, fc, Ls, XPall);
        pack_slice<5>(b, fc, Ls, XPall);
        pack_slice<4>(b, fc, Ls, XPall);
        pack_slice<3>(b, fc, Ls, XPall);
        pack_slice<2>(b, fc, Ls, XPall);
        pack_slice<1>(b, fc, Ls, XPall);
        pack_slice<0>(b, fc, Ls, XPall);
    }
}

// standalone psi kernel (tier B)
__global__ __launch_bounds__(256) void psi_gemm_all(const float* __restrict__ w,
                                                    const short* __restrict__ DT,
                                                    short* __restrict__ PSIall) {
    __shared__ short As[64][72];
    __shared__ short Bs[128][72];
    __shared__ int colInfo[128];
    psi_body(blockIdx.y * gridDim.x + blockIdx.x, w, DT, PSIall, As, Bs, colInfo);
}

// ---------------- per-l x packing (tier B/C fallback) ----------------
template <int d>
__global__ __launch_bounds__(256) void pack_x(const float* __restrict__ x,
                                              short* __restrict__ XP, int off) {
    constexpr int sz = d * d;
    constexpr int K = 128 * d;
    const int fc = blockIdx.x, b = blockIdx.y;
    __shared__ short Ls[64][sz + 1];
    const int tid = threadIdx.x;
    const float* xb = x + ((size_t)b * 128 + fc * 64) * 455 + off;
    for (int e = tid; e < 64 * sz; e += 256) {
        int ff = e / sz, t = e - ff * sz;
        Ls[ff][t] = f2bf(xb[(size_t)ff * 455 + t]);
    }
    __syncthreads();
    for (int e = tid; e < 64 * sz; e += 256) {
        int i = e / (64 * d);
        int rem = e - i * (64 * d);
        int ff = rem / d, u = rem - ff * d;
        XP[((size_t)b * d + i) * K + (fc * 64 + ff) * d + u] = Ls[ff][u * d + i];
    }
}

// ---------------- Phase 1 fallback: per-l GEMM M=16384(fg), N=d^2(c), K=512 ----------------
template <int d>
__global__ __launch_bounds__(256) void psi_gemm(const float* __restrict__ w,
                                                const short* __restrict__ DT,
                                                short* __restrict__ PSI, int off) {
    constexpr int sz = d * d;
    constexpr int KP = 128 * d;
    const int mt = blockIdx.x;
    const int nt = blockIdx.y;
    const int tid = threadIdx.x, wave = tid >> 6, lane = tid & 63;
    const int wm = (wave & 1) * 32, wn = (wave >> 1) * 64;

    __shared__ short As[64][72];
    __shared__ short Bs[128][72];

    const float* Ag = w + (size_t)(mt * 64) * 512;
    f32x4 acc[2][4] = {};

    for (int k0 = 0; k0 < 512; k0 += 64) {
        __syncthreads();
#pragma unroll
        for (int c = 0; c < 4; ++c) {
            int e = (tid + c * 256) * 4;
            int r = e >> 6, cc = e & 63;
            float4 v = *reinterpret_cast<const float4*>(Ag + (size_t)r * 512 + k0 + cc);
            short4v s;
            s.x = f2bf(v.x); s.y = f2bf(v.y); s.z = f2bf(v.z); s.w = f2bf(v.w);
            *reinterpret_cast<short4v*>(&As[r][cc]) = s;
        }
#pragma unroll
        for (int c = 0; c < 4; ++c) {
            int ch = tid + c * 256;
            int r = ch >> 3, cc = (ch & 7) * 8;
            int gc = nt * 128 + r;
            int row = off + (gc < sz ? gc : 0);
            short8 v = *reinterpret_cast<const short8*>(DT + (size_t)row * 512 + k0 + cc);
            *reinterpret_cast<short8*>(&Bs[r][cc]) = v;
        }
        __syncthreads();
#pragma unroll
        for (int kf = 0; kf < 2; ++kf) {
            const int kc = kf * 32 + (lane >> 4) * 8;
            short8 af[2], bfr[4];
#pragma unroll
            for (int mi = 0; mi < 2; ++mi)
                af[mi] = *reinterpret_cast<const short8*>(&As[wm + mi * 16 + (lane & 15)][kc]);
#pragma unroll
            for (int ni = 0; ni < 4; ++ni)
                bfr[ni] = *reinterpret_cast<const short8*>(&Bs[wn + ni * 16 + (lane & 15)][kc]);
#pragma unroll
            for (int mi = 0; mi < 2; ++mi)
#pragma unroll
                for (int ni = 0; ni < 4; ++ni)
                    acc[mi][ni] = __builtin_amdgcn_mfma_f32_16x16x32_bf16(
                        as_bf8(af[mi]), as_bf8(bfr[ni]), acc[mi][ni], 0, 0, 0);
        }
    }

    const float s1 = 0.044194173824159216f;  // 1/sqrt(512)
#pragma unroll
    for (int mi = 0; mi < 2; ++mi)
#pragma unroll
        for (int ni = 0; ni < 4; ++ni) {
            int cix = nt * 128 + wn + ni * 16 + (lane & 15);
            if (cix < sz) {
                int u = cix / d, v = cix - u * d;
#pragma unroll
                for (int r = 0; r < 4; ++r) {
                    int m = mt * 64 + wm + mi * 16 + (lane >> 4) * 4 + r;
                    int f = m >> 7, g = m & 127;
                    PSI[(size_t)(g * d + v) * KP + f * d + u] = f2bf(acc[mi][ni][r] * s1);
                }
            }
        }
}

// ---------------- Phase 2 tier A: templated-l, 64x128 tile, single-buffered ----------------
// Empirical optimum of the schedule/tile variants tested (rounds 2-12).  Simple loop:
// barrier -> STAGE(t) -> barrier(vmcnt drain) -> COMPUTE(t).  24.5 KB LDS.
template <int l>
static __device__ __forceinline__ void so3_body(int pp,
                                                const short* __restrict__ XPall,
                                                const short* __restrict__ PSIall,
                                                float* __restrict__ out,
                                                short* As, short* Bs) {
    constexpr int d = 2 * l + 1;
    constexpr int K = 128 * d;
    constexpr int S = 4 * d * d;                     // segment size, S % 8 == 4
    constexpr int q = S >> 3;
    constexpr int off = l * (2 * l - 1) * (2 * l + 1) / 3;
    constexpr int mtiles = 2 * d;

    const int xcd = pp & 7, pos = pp >> 3;           // per-segment bijective XCD chunk
    const int local = (xcd < 4 ? xcd * (q + 1) : 4 * (q + 1) + (xcd - 4) * q) + pos;
    const int mt = local % mtiles, nt = local / mtiles;   // consecutive locals share nt

    const int tid = threadIdx.x, wave = tid >> 6, lane = tid & 63;
    const int wm = (wave & 1) * 32, wn = (wave >> 1) * 64;

    const short* Ag = PSIall + PSIOFF_C[l] + (size_t)(mt * 64) * K;
    const short* Bg = XPall + XPOFF_C[l] + (size_t)(nt * 128) * K;

    const int lrow = lane >> 3;                      // 0..7
    const int scol = (((lane & 7) ^ lrow) << 3);     // inverse-swizzled global slot (shorts)

    f32x4 acc[2][4] = {};

#pragma unroll 1
    for (int k0 = 0; k0 < K; k0 += 64) {
        __syncthreads();                             // all waves done reading prev tile
#pragma unroll
        for (int c = 0; c < 2; ++c)                  // A: rows wave*16 + 8c + lrow
            glds16(Ag + (size_t)(wave * 16 + 8 * c + lrow) * K + k0 + scol,
                   &As[(wave * 16 + 8 * c) * 64]);
#pragma unroll
        for (int c = 0; c < 4; ++c)                  // B: rows wave*32 + 8c + lrow
            glds16(Bg + (size_t)(wave * 32 + 8 * c + lrow) * K + k0 + scol,
                   &Bs[(wave * 32 + 8 * c) * 64]);
        __syncthreads();                             // vmcnt drained -> tile ready
#pragma unroll
        for (int kf = 0; kf < 2; ++kf) {
            const int so = (((kf * 4 + (lane >> 4)) ^ (lane & 7)) << 3);
            short8 af[2], bfr[4];
#pragma unroll
            for (int mi = 0; mi < 2; ++mi)
                af[mi] = *reinterpret_cast<const short8*>(
                    &As[(wm + mi * 16 + (lane & 15)) * 64 + so]);
#pragma unroll
            for (int ni = 0; ni < 4; ++ni)
                bfr[ni] = *reinterpret_cast<const short8*>(
                    &Bs[(wn + ni * 16 + (lane & 15)) * 64 + so]);
#pragma unroll
            for (int mi = 0; mi < 2; ++mi)
#pragma unroll
                for (int ni = 0; ni < 4; ++ni)
                    acc[mi][ni] = __builtin_amdgcn_mfma_f32_16x16x32_bf16(
                        as_bf8(af[mi]), as_bf8(bfr[ni]), acc[mi][ni], 0, 0, 0);
        }
    }

    const float s2 = rsqrtf(128.0f * (float)d);      // folds: d is constexpr
#pragma unroll
    for (int mi = 0; mi < 2; ++mi)
#pragma unroll
        for (int ni = 0; ni < 4; ++ni) {
            int n = nt * 128 + wn + ni * 16 + (lane & 15);
            int b = n / d, i = n - b * d;            // constexpr d -> magic mul
#pragma unroll
            for (int r = 0; r < 4; ++r) {
                int m = mt * 64 + wm + mi * 16 + (lane >> 4) * 4 + r;
                int g = m / d, v = m - g * d;
                out[((size_t)b * 128 + g) * 455 + off + v * d + i] = acc[mi][ni][r] * s2;
            }
        }
}

// segment starts, descending l (heavy first): sizes 4d^2, total 1820
__global__ __launch_bounds__(256) void so3_gemm_all(const short* __restrict__ XPall,
                                                    const short* __restrict__ PSIall,
                                                    float* __restrict__ out) {
    __shared__ short As[64 * 64];      // 8 KB
    __shared__ short Bs[128 * 64];     // 16 KB  (24.5 KB total -> max co-residency)
    const int p = blockIdx.x;
    if (p < 676)       so3_body<6>(p,        XPall, PSIall, out, As, Bs);
    else if (p < 1160) so3_body<5>(p - 676,  XPall, PSIall, out, As, Bs);
    else if (p < 1484) so3_body<4>(p - 1160, XPall, PSIall, out, As, Bs);
    else if (p < 1680) so3_body<3>(p - 1484, XPall, PSIall, out, As, Bs);
    else if (p < 1780) so3_body<2>(p - 1680, XPall, PSIall, out, As, Bs);
    else if (p < 1816) so3_body<1>(p - 1780, XPall, PSIall, out, As, Bs);
    else               so3_body<0>(p - 1816, XPall, PSIall, out, As, Bs);
}

// ---------------- Phase 2 tier B/C: round-1 verified per-l GEMM (reg-staged) ---------------
template <int d>
__global__ __launch_bounds__(256) void so3_gemm_fb(const short* __restrict__ XP,
                                                   const short* __restrict__ PSI,
                                                   float* __restrict__ out, int off) {
    constexpr int K = 128 * d;
    constexpr int GX = 2 * d;
    constexpr int NWG = 4 * d * d;
    int id = blockIdx.y * gridDim.x + blockIdx.x;
    {
        constexpr int q = NWG >> 3, rr = NWG & 7;
        int xcd = id & 7, pos = id >> 3;
        id = (xcd < rr ? xcd * (q + 1) : rr * (q + 1) + (xcd - rr) * q) + pos;
    }
    const int mt = id % GX, nt = id / GX;
    const int tid = threadIdx.x, wave = tid >> 6, lane = tid & 63;
    const int wm = (wave & 1) * 32, wn = (wave >> 1) * 64;

    __shared__ short As[64][72];
    __shared__ short Bs[128][72];

    const short* Ag = PSI + (size_t)(mt * 64) * K;
    const short* Bg = XP + (size_t)(nt * 128) * K;
    f32x4 acc[2][4] = {};

    for (int k0 = 0; k0 < K; k0 += 64) {
        __syncthreads();
#pragma unroll
        for (int c = 0; c < 2; ++c) {
            int ch = tid + c * 256;
            int r = ch >> 3, cc = (ch & 7) * 8;
            *reinterpret_cast<short8*>(&As[r][cc]) =
                *reinterpret_cast<const short8*>(Ag + (size_t)r * K + k0 + cc);
        }
#pragma unroll
        for (int c = 0; c < 4; ++c) {
            int ch = tid + c * 256;
            int r = ch >> 3, cc = (ch & 7) * 8;
            *reinterpret_cast<short8*>(&Bs[r][cc]) =
                *reinterpret_cast<const short8*>(Bg + (size_t)r * K + k0 + cc);
        }
        __syncthreads();
#pragma unroll
        for (int kf = 0; kf < 2; ++kf) {
            const int kc = kf * 32 + (lane >> 4) * 8;
            short8 af[2], bfr[4];
#pragma unroll
            for (int mi = 0; mi < 2; ++mi)
                af[mi] = *reinterpret_cast<const short8*>(&As[wm + mi * 16 + (lane & 15)][kc]);
#pragma unroll
            for (int ni = 0; ni < 4; ++ni)
                bfr[ni] = *reinterpret_cast<const short8*>(&Bs[wn + ni * 16 + (lane & 15)][kc]);
#pragma unroll
            for (int mi = 0; mi < 2; ++mi)
#pragma unroll
                for (int ni = 0; ni < 4; ++ni)
                    acc[mi][ni] = __builtin_amdgcn_mfma_f32_16x16x32_bf16(
                        as_bf8(af[mi]), as_bf8(bfr[ni]), acc[mi][ni], 0, 0, 0);
        }
    }

    const float s2 = rsqrtf(128.0f * (float)d);
#pragma unroll
    for (int mi = 0; mi < 2; ++mi)
#pragma unroll
        for (int ni = 0; ni < 4; ++ni) {
            int n = nt * 128 + wn + ni * 16 + (lane & 15);
            int b = n / d, i = n - b * d;
#pragma unroll
            for (int r = 0; r < 4; ++r) {
                int m = mt * 64 + wm + mi * 16 + (lane >> 4) * 4 + r;
                int g = m / d, v = m - g * d;
                out[((size_t)b * 128 + g) * 455 + off + v * d + i] = acc[mi][ni][r] * s2;
            }
        }
}

// ---------------- drivers ----------------
template <int l>
static void run_l_fb(const float* x, const float* w, const short* DT, short* PSIbase,
                     short* XP, float* out, bool fused, hipStream_t stream) {
    constexpr int d = 2 * l + 1;
    const int off = OFFS_H[l];
    if (!fused) {
        constexpr int sz = d * d;
        constexpr int ntiles = (sz + 127) / 128;
        psi_gemm<d><<<dim3(256, ntiles), 256, 0, stream>>>(w, DT, PSIbase, off);
    }
    pack_x<d><<<dim3(2, 256), 256, 0, stream>>>(x, XP, off);
    const short* P = fused ? (PSIbase + PSIOFF_H[l]) : PSIbase;
    so3_gemm_fb<d><<<dim3(2 * d, 2 * d), 256, 0, stream>>>(XP, P, out, off);
}

extern "C" void kernel_launch(void* const* d_in, const int* in_sizes, int n_in,
                              void* d_out, int out_size, void* d_ws, size_t ws_size,
                              hipStream_t stream) {
    const float* x = (const float*)d_in[0];   // [256,128,455]
    const float* w = (const float*)d_in[1];   // [128,128,512]
    const float* D = (const float*)d_in[2];   // [512,455]
    float* out = (float*)d_out;

    char* ws = (char*)d_ws;
    const size_t dtBytes      = (size_t)455 * 512 * 2;      //    465,920
    const size_t psiAllBytes  = (size_t)7454720 * 2;        // 14,909,440 (all-l PSI)
    const size_t psiSlotBytes = (size_t)1664 * 1664 * 2;    //  5,537,792 (l=6 slot)
    const size_t xpL6Bytes    = (size_t)3328 * 1664 * 2;    // 11,067,392 (l=6 XP2)
    const size_t xpAllBytes   = (size_t)14909440 * 2;       // 29,818,880 (all-l XP2)

    short* DT = (short*)ws;
    transpose_D<<<(455 * 512 + 255) / 256, 256, 0, stream>>>(D, DT);

    if (ws_size >= dtBytes + psiAllBytes + xpAllBytes) {            // Tier A: 45.2 MB
        short* PSIall = (short*)(ws + dtBytes);
        short* XPall  = (short*)(ws + dtBytes + psiAllBytes);
        prep_all<<<dim3(2048), 256, 0, stream>>>(w, DT, x, PSIall, XPall);
        so3_gemm_all<<<dim3(1820), 256, 0, stream>>>(XPall, PSIall, out);
        return;
    }

    const bool fused = ws_size >= dtBytes + psiAllBytes + xpL6Bytes;  // Tier B: 26.4 MB
    short* PSIbase = (short*)(ws + dtBytes);
    short* XP = (short*)(ws + dtBytes + (fused ? psiAllBytes : psiSlotBytes));
    if (fused)
        psi_gemm_all<<<dim3(4, 256), 256, 0, stream>>>(w, DT, PSIbase);

    run_l_fb<0>(x, w, DT, PSIbase, XP, out, fused, stream);
    run_l_fb<1>(x, w, DT, PSIbase, XP, out, fused, stream);
    run_l_fb<2>(x, w, DT, PSIbase, XP, out, fused, stream);
    run_l_fb<3>(x, w, DT, PSIbase, XP, out, fused, stream);
    run_l_fb<4>(x, w, DT, PSIbase, XP, out, fused, stream);
    run_l_fb<5>(x, w, DT, PSIbase, XP, out, fused, stream);
    run_l_fb<6>(x, w, DT, PSIbase, XP, out, fused, stream);
}